// Round 4
// baseline (102.958 us; speedup 1.0000x reference)
//
#include <hip/hip_runtime.h>
#include <math.h>

#define LMAX 10
#define NCOL 121            // (LMAX+1)^2
#define PPB  64             // points per block
#define TILE4 (PPB * NCOL / 4)   // 1936 float4 per block tile

typedef float f4_t __attribute__((ext_vector_type(4)));

struct Tab {
    float K[66];   // K(l,m) (* sqrt2 for m>0), index l(l+1)/2+m
    float A[66];   // (2l-1)/(l-m)    for l>=m+2
    float B[66];   // (l+m-1)/(l-m)   for l>=m+2
};

// Emit chain for fixed M: P(l,M) for l=M..LMAX, scaled by K * rf^l (and cos/sin(M phi))
template<int M>
__device__ __forceinline__ void chain(const Tab& t, float* __restrict__ row,
                                      float pmm, float rfm, float rf, float x,
                                      float cm, float sm) {
    {
        float v = t.K[M * (M + 1) / 2 + M] * pmm * rfm;
        if constexpr (M == 0) row[0] = v;
        else { row[M * M + 2 * M] = v * cm; row[M * M] = v * sm; }
    }
    if constexpr (M < LMAX) {
        float p0 = pmm;
        float p1 = x * (float)(2 * M + 1) * pmm;
        float rfl = rfm * rf;
        {
            constexpr int L = M + 1;
            float v = t.K[L * (L + 1) / 2 + M] * p1 * rfl;
            if constexpr (M == 0) row[L * L + L] = v;
            else { row[L * L + L + M] = v * cm; row[L * L + L - M] = v * sm; }
        }
#pragma unroll
        for (int ll = M + 2; ll <= LMAX; ++ll) {
            int ti = ll * (ll + 1) / 2 + M;
            float p2 = t.A[ti] * x * p1 - t.B[ti] * p0;
            p0 = p1; p1 = p2;
            rfl *= rf;
            float v = t.K[ti] * p1 * rfl;
            int jb = ll * ll + ll;
            if constexpr (M == 0) row[jb] = v;
            else { row[jb + M] = v * cm; row[jb - M] = v * sm; }
        }
    }
}

template<bool FULL>
__global__ __launch_bounds__(256)
void sh_kernel(const float* __restrict__ in, float* __restrict__ out,
               int n, int blk_off, Tab t) {
    __shared__ f4_t lds4[TILE4];               // [point][j], == output layout
    float* lds = (float*)lds4;

    const int bid = blockIdx.x + blk_off;
    const int p = threadIdx.x & 63;            // local point
    const int s = threadIdx.x >> 6;            // m-group (wave-uniform)
    const long long gp = (long long)bid * PPB + p;

    if (FULL || gp < n) {
        const float lon = in[gp * 3 + 0];
        const float lat = in[gp * 3 + 1];
        const float r   = in[gp * 3 + 2];

        const float D2R  = 0.017453292519943295f;
        const float PI_F = 3.14159265358979323846f;

        float phi   = (lon + 180.0f) * D2R;
        float theta = fminf(fmaxf((90.0f - lat) * D2R, 1e-7f), PI_F - 1e-7f);
        float x = __cosf(theta);
        x = fminf(fmaxf(x, -1.0f + 1e-7f), 1.0f - 1e-7f);
        float somx2 = sqrtf(fmaxf((1.0f - x) * (1.0f + x), 0.0f));
        float rf  = 6371000.0f / r;
        float rf2 = rf * rf;
        float rf3 = rf2 * rf;
        float rf5 = rf3 * rf2;

        float c1, s1;
        __sincosf(phi, &s1, &c1);
        float c2 = c1 * c1 - s1 * s1, s2 = 2.0f * c1 * s1;
        float c3 = c2 * c1 - s2 * s1, s3 = s2 * c1 + c2 * s1;
        float c4 = c2 * c2 - s2 * s2, s4 = 2.0f * c2 * s2;
        float c5 = c4 * c1 - s4 * s1, s5 = s4 * c1 + c4 * s1;

        float sx2 = somx2 * somx2;
        float sx3 = sx2 * somx2;
        float sx5 = sx3 * sx2;

        float* row = lds + p * NCOL;

#define ROT(cm, sm, ck, sk) { float cn = cm * ck - sm * sk; sm = sm * ck + cm * sk; cm = cn; }

        // m-sets balanced by chain length: {0,5,10}=18, {1,6,9}=17, {2,7,8}=16, {3,4}=15
        switch (s) {
        case 0: {
            float pmm = 1.0f, rfm = 1.0f, cm = 1.0f, sm = 0.0f;
            chain<0>(t, row, pmm, rfm, rf, x, cm, sm);
            pmm *= -945.0f    * sx5; rfm *= rf5; ROT(cm, sm, c5, s5);   // 1*3*5*7*9
            chain<5>(t, row, pmm, rfm, rf, x, cm, sm);
            pmm *= -692835.0f * sx5; rfm *= rf5; ROT(cm, sm, c5, s5);   // 11*13*15*17*19
            chain<10>(t, row, pmm, rfm, rf, x, cm, sm);
        } break;
        case 1: {
            float pmm = -somx2, rfm = rf, cm = c1, sm = s1;
            chain<1>(t, row, pmm, rfm, rf, x, cm, sm);
            pmm *= -10395.0f * sx5; rfm *= rf5; ROT(cm, sm, c5, s5);    // 3*5*7*9*11
            chain<6>(t, row, pmm, rfm, rf, x, cm, sm);
            pmm *= -3315.0f  * sx3; rfm *= rf3; ROT(cm, sm, c3, s3);    // 13*15*17
            chain<9>(t, row, pmm, rfm, rf, x, cm, sm);
        } break;
        case 2: {
            float pmm = 3.0f * sx2, rfm = rf2, cm = c2, sm = s2;
            chain<2>(t, row, pmm, rfm, rf, x, cm, sm);
            pmm *= -45045.0f * sx5; rfm *= rf5; ROT(cm, sm, c5, s5);    // 5*7*9*11*13
            chain<7>(t, row, pmm, rfm, rf, x, cm, sm);
            pmm *= -15.0f * somx2;  rfm *= rf;  ROT(cm, sm, c1, s1);    // 15
            chain<8>(t, row, pmm, rfm, rf, x, cm, sm);
        } break;
        default: {
            float pmm = -15.0f * sx3, rfm = rf3, cm = c3, sm = s3;
            chain<3>(t, row, pmm, rfm, rf, x, cm, sm);
            pmm *= -7.0f * somx2; rfm *= rf; ROT(cm, sm, c1, s1);       // 7
            chain<4>(t, row, pmm, rfm, rf, x, cm, sm);
        } break;
        }
#undef ROT
    }
    __syncthreads();

    // Epilogue: tile already in output order -> pure linear float4 copy
    // A/B vs R3: plain stores (no nontemporal flag), everything else identical.
    f4_t* __restrict__ dst = (f4_t*)out + (long long)bid * TILE4;
    if (FULL) {
#pragma unroll
        for (int k = 0; k < 7; ++k)
            dst[threadIdx.x + k * 256] = lds4[threadIdx.x + k * 256];
        if (threadIdx.x < TILE4 - 7 * 256)   // 1936 - 1792 = 144
            dst[threadIdx.x + 7 * 256] = lds4[threadIdx.x + 7 * 256];
    } else {
        const long long lim4 = ((long long)n * NCOL + 3) / 4;
        const long long base4 = (long long)bid * TILE4;
        for (int f = threadIdx.x; f < TILE4; f += 256) {
            if (base4 + f < lim4)
                dst[f] = lds4[f];
        }
    }
}

extern "C" void kernel_launch(void* const* d_in, const int* in_sizes, int n_in,
                              void* d_out, int out_size, void* d_ws, size_t ws_size,
                              hipStream_t stream) {
    const float* in = (const float*)d_in[0];
    float* out = (float*)d_out;
    const int n = in_sizes[0] / 3;

    Tab t;
    double fact[2 * LMAX + 1];
    fact[0] = 1.0;
    for (int i = 1; i <= 2 * LMAX; ++i) fact[i] = fact[i - 1] * (double)i;
    for (int l = 0; l <= LMAX; ++l) {
        for (int m = 0; m <= l; ++m) {
            int ti = l * (l + 1) / 2 + m;
            double k = sqrt((2.0 * l + 1.0) * fact[l - m] / fact[l + m]);
            if (m > 0) k *= sqrt(2.0);
            t.K[ti] = (float)k;
            if (l >= m + 2) {
                t.A[ti] = (float)((2.0 * l - 1.0) / (double)(l - m));
                t.B[ti] = (float)(((double)(l + m) - 1.0) / (double)(l - m));
            } else {
                t.A[ti] = 0.0f; t.B[ti] = 0.0f;
            }
        }
    }

    const int full_blocks = n / PPB;
    const int tail_pts    = n - full_blocks * PPB;
    if (full_blocks > 0)
        sh_kernel<true><<<full_blocks, 256, 0, stream>>>(in, out, n, 0, t);
    if (tail_pts > 0)
        sh_kernel<false><<<1, 256, 0, stream>>>(in, out, n, full_blocks, t);
}